// Round 11
// baseline (1070.822 us; speedup 1.0000x reference)
//
#include <hip/hip_runtime.h>

#define NN 12288
#define OUTF 64
#define ALPHA 0.2f
#define C1 6.0f
#define KSP 8
#define KRANGE (NN / KSP)    /* 1536 per block */
#define ITERS (KRANGE / 64)  /* 24 */

typedef unsigned short u16;
typedef unsigned int u32;
typedef unsigned long long u64;
typedef _Float16 half8 __attribute__((ext_vector_type(8)));
typedef float floatx4 __attribute__((ext_vector_type(4)));
typedef int intx4 __attribute__((ext_vector_type(4)));

union H16 { u16 u; _Float16 h; };
__device__ __forceinline__ u16 f2h(float f) { H16 c; c.h = (_Float16)f; return c.u; }

// async global->LDS DMA, 16 B per lane; lds dest = wave-uniform base + lane*16
__device__ __forceinline__ void g2l16(const void* g, void* l) {
  __builtin_amdgcn_global_load_lds(
      (const __attribute__((address_space(1))) void*)g,
      (__attribute__((address_space(3))) void*)l, 16, 0, 0);
}

// ---------------- K1: h = X@W, per-node scalars, Btf in MFMA-fragment order --------------
// 192 blocks x 64 nodes: one 32-KB W LDS-load amortized over 64 nodes (was 16).
// Btf chunk (k32, n): 64 lanes x 16 B contiguous; lane element j' = B_row(n*16+lane%16),
// source node k32*32 + (lane/16)*8 + j'.  B_row r: r<64: e1*h[r]; r==64: e1; 65..79: 0;
// 80..143: e2*h[r-80]; r==144: e2; 145..159: 0.   e1=exp(s2-C1), e2=exp(a*s2).
__global__ __launch_bounds__(256) void k1_prep(
    const float* __restrict__ inp, const float* __restrict__ W, const float* __restrict__ a,
    u16* __restrict__ e1h, u16* __restrict__ thh,
    float* __restrict__ f1g, float* __restrict__ f2g, u16* __restrict__ Btf)
{
  __shared__ float Wl[128 * 64];               // 32 KB
  __shared__ float hsm[64][65];                // 16.6 KB
  __shared__ float e1sm[64], e2sm[64];
  const int tid = threadIdx.x, wave = tid >> 6, lane = tid & 63;
  const int b = blockIdx.x;                    // 64-node group
  for (int t = tid; t < 2048; t += 256)
    ((float4*)Wl)[t] = ((const float4*)W)[t];
  const float a1l = a[lane], a2l = a[OUTF + lane];
  __syncthreads();
  for (int jl = 0; jl < 16; ++jl) {
    const int jn = wave * 16 + jl;             // local node 0..63
    const int j = b * 64 + jn;
    const float4* xp = (const float4*)(inp + (size_t)j * 128);
    float h = 0.f;
#pragma unroll
    for (int c4 = 0; c4 < 32; ++c4) {
      float4 v = xp[c4];
      const int k = c4 * 4;
      h += v.x * Wl[k * 64 + lane] + v.y * Wl[(k + 1) * 64 + lane]
         + v.z * Wl[(k + 2) * 64 + lane] + v.w * Wl[(k + 3) * 64 + lane];
    }
    float p1 = h * a1l, p2 = h * a2l;
#pragma unroll
    for (int off = 32; off > 0; off >>= 1) { p1 += __shfl_xor(p1, off); p2 += __shfl_xor(p2, off); }
    hsm[jn][lane] = h;
    if (lane == 0) {
      const float s1 = p1, s2 = p2;
      const float e1 = expf(s2 - C1), e2 = expf(ALPHA * s2);
      e1sm[jn] = e1; e2sm[jn] = e2;
      e1h[j] = f2h(e1);
      thh[j] = f2h(expf(-s1 - C1));            // pos branch iff e1h[j] > thh[i] (u16-monotone)
      f1g[j] = expf(s1 + C1);
      f2g[j] = expf(ALPHA * s1);
    }
  }
  __syncthreads();
  // phase B: block covers 2 full k32 slabs (k32 = b*2+s). 1280 uint4 items, 5/thread.
  for (int cc = tid; cc < 1280; cc += 256) {
    const int s = cc / 640, rem = cc - s * 640;
    const int n = rem >> 6, l = rem & 63;
    const int r = n * 16 + (l & 15);
    const int jb = s * 32 + (l >> 4) * 8;      // local node base for this item's 8 elements
    u32 wpk[4];
#pragma unroll
    for (int p = 0; p < 4; ++p) {
      u16 hh[2];
#pragma unroll
      for (int q2 = 0; q2 < 2; ++q2) {
        const int jj = jb + p * 2 + q2;
        float v;
        if (r < 64)        v = e1sm[jj] * hsm[jj][r];
        else if (r == 64)  v = e1sm[jj];
        else if (r < 80)   v = 0.f;
        else if (r < 144)  v = e2sm[jj] * hsm[jj][r - 80];
        else if (r == 144) v = e2sm[jj];
        else               v = 0.f;
        hh[q2] = f2h(v);
      }
      wpk[p] = (u32)hh[0] | ((u32)hh[1] << 16);
    }
    ((uint4*)Btf)[(size_t)((b * 2 + s) * 10 + n) * 64 + l] = make_uint4(wpk[0], wpk[1], wpk[2], wpk[3]);
  }
}

// pack helper: build branch-resolved mask bytes from an adj register tile
#define PACK_MASKS(dst1, dst2, AJ, EVV)                                                    \
  {                                                                                        \
    u32 ev8[8] = {EVV.x & 0xFFFFu, EVV.x >> 16, EVV.y & 0xFFFFu, EVV.y >> 16,              \
                  EVV.z & 0xFFFFu, EVV.z >> 16, EVV.w & 0xFFFFu, EVV.w >> 16};             \
    _Pragma("unroll")                                                                      \
    for (int p = 0; p < 4; ++p) {                                                          \
      const int av[8] = {AJ[p][0].x, AJ[p][0].y, AJ[p][0].z, AJ[p][0].w,                   \
                         AJ[p][1].x, AJ[p][1].y, AJ[p][1].z, AJ[p][1].w};                  \
      u32 b1 = 0, b2 = 0;                                                                  \
      _Pragma("unroll")                                                                    \
      for (int e = 0; e < 8; ++e) {                                                        \
        const bool nbr = av[e] > 0;                                                        \
        const bool up = ev8[e] > (u32)thu[p];                                              \
        b1 |= (u32)(nbr && up) << e;                                                       \
        b2 |= (u32)(nbr && !up) << e;                                                      \
      }                                                                                    \
      ((unsigned char*)&dst1[p * 32 + prow])[pcol] = (unsigned char)b1;                    \
      ((unsigned char*)&dst2[p * 32 + prow])[pcol] = (unsigned char)b2;                    \
    }                                                                                      \
  }

// ---------------- K2: FUSED adj-pack + LDS-staged bit-masked dual GEMM -------------------
// 768 blocks = 96 mpos x 8 ksplit. 2-iteration-ahead adj pipeline: pack slab s+1 at top of
// iter s from registers loaded during iter s-1 (zero exposed latency), then issue slab s+2
// loads. B slabs via double-buffered global_load_lds DMA. One barrier per iter.
__global__ __launch_bounds__(256, 2) void k2_main(
    const int* __restrict__ adj, const u16* __restrict__ e1h, const u16* __restrict__ thh,
    const u16* __restrict__ Btf, float* __restrict__ part)
{
  __shared__ u16 sB[2][10240];                 // 40 KB B slabs
  __shared__ u64 m1s[2][128];                  // 2 KB pos-branch masks
  __shared__ u64 m2s[2][128];                  // 2 KB neg-branch masks
  const int tid = threadIdx.x;
  const int wave = tid >> 6, lane = tid & 63;
  const int quad = lane >> 4, lr = lane & 15;
  const int mpos = (int)blockIdx.x >> 3;
  const int ks = (int)blockIdx.x & 7;
  const int mbase = mpos * 128;
  const int k0 = ks * KRANGE;

  // pack role: rows prow+32p (p=0..3), cols pcol*8..+8 of each k64 slab
  const int prow = tid >> 3, pcol = tid & 7;
  u16 thu[4];
#pragma unroll
  for (int p = 0; p < 4; ++p) thu[p] = thh[mbase + p * 32 + prow];
  const int* aB = adj + (size_t)(mbase + prow) * NN + k0 + pcol * 8;
  const u16* eB = e1h + k0 + pcol * 8;

  floatx4 acc[2][10];
#pragma unroll
  for (int t = 0; t < 2; ++t)
#pragma unroll
    for (int n = 0; n < 10; ++n) acc[t][n] = (floatx4){0.f, 0.f, 0.f, 0.f};

  intx4 ajb[2][4][2];                          // slab s lives in ajb[s&1]
  uint4 evb[2];

  // ---- prologue ----
  {
    const char* src = (const char*)(Btf + ((size_t)(k0 >> 5)) * 5120);
#pragma unroll
    for (int i = 0; i < 5; ++i)                // DMA B slab 0
      g2l16(src + i * 4096 + tid * 16, (char*)&sB[0][0] + i * 4096 + wave * 1024);
#pragma unroll
    for (int p = 0; p < 4; ++p) {              // adj slab 0
      ajb[0][p][0] = __builtin_nontemporal_load((const intx4*)(aB + (size_t)p * 32 * NN));
      ajb[0][p][1] = __builtin_nontemporal_load((const intx4*)(aB + (size_t)p * 32 * NN + 4));
    }
    evb[0] = *(const uint4*)eB;
    PACK_MASKS(m1s[0], m2s[0], ajb[0], evb[0]) // masks slab 0
#pragma unroll
    for (int p = 0; p < 4; ++p) {              // adj slab 1 (in flight across barrier)
      ajb[1][p][0] = __builtin_nontemporal_load((const intx4*)(aB + (size_t)p * 32 * NN + 64));
      ajb[1][p][1] = __builtin_nontemporal_load((const intx4*)(aB + (size_t)p * 32 * NN + 68));
    }
    evb[1] = *(const uint4*)(eB + 64);
  }

  for (int it = 0; it < ITERS; ++it) {
    __syncthreads();                           // sB[cur], m[cur] ready
    const int cur = it & 1, nxt = cur ^ 1;
    if (it + 1 < ITERS) {                      // DMA B slab it+1
      const char* src = (const char*)(Btf + ((size_t)(k0 >> 5) + (it + 1) * 2) * 5120);
#pragma unroll
      for (int i = 0; i < 5; ++i)
        g2l16(src + i * 4096 + tid * 16, (char*)&sB[nxt][0] + i * 4096 + wave * 1024);
      PACK_MASKS(m1s[nxt], m2s[nxt], ajb[nxt], evb[nxt])  // masks slab it+1 (regs ready)
    }
    if (it + 2 < ITERS) {                      // adj slab it+2 -> ajb[cur] (consumed already)
      const int koff = (it + 2) * 64;
#pragma unroll
      for (int p = 0; p < 4; ++p) {
        ajb[cur][p][0] = __builtin_nontemporal_load((const intx4*)(aB + (size_t)p * 32 * NN + koff));
        ajb[cur][p][1] = __builtin_nontemporal_load((const intx4*)(aB + (size_t)p * 32 * NN + koff + 4));
      }
      evb[cur] = *(const uint4*)(eB + koff);
    }

    // ---- MFMA on [cur] ----
    u64 w1[2], w2[2];
    w1[0] = m1s[cur][wave * 32 + lr];      w1[1] = m1s[cur][wave * 32 + 16 + lr];
    w2[0] = m2s[cur][wave * 32 + lr];      w2[1] = m2s[cur][wave * 32 + 16 + lr];
#pragma unroll
    for (int h = 0; h < 2; ++h) {
      const u32 sh = (u32)(h * 32 + quad * 8);
      union { half8 v; u16 s[8]; } A1[2], A2[2];
      const u32 m1a = (u32)(w1[0] >> sh) & 0xFFu, m2a = (u32)(w2[0] >> sh) & 0xFFu;
      const u32 m1b = (u32)(w1[1] >> sh) & 0xFFu, m2b = (u32)(w2[1] >> sh) & 0xFFu;
#pragma unroll
      for (int e = 0; e < 8; ++e) {
        A1[0].s[e] = ((m1a >> e) & 1u) ? (u16)0x3C00 : (u16)0;
        A2[0].s[e] = ((m2a >> e) & 1u) ? (u16)0x3C00 : (u16)0;
        A1[1].s[e] = ((m1b >> e) & 1u) ? (u16)0x3C00 : (u16)0;
        A2[1].s[e] = ((m2b >> e) & 1u) ? (u16)0x3C00 : (u16)0;
      }
      const u16* bp = &sB[cur][h * 5120];
#pragma unroll
      for (int n = 0; n < 10; ++n) {
        half8 Bv = *(const half8*)(bp + (n * 64 + lane) * 8);
        acc[0][n] = __builtin_amdgcn_mfma_f32_16x16x32_f16(n < 5 ? A1[0].v : A2[0].v, Bv,
                                                           acc[0][n], 0, 0, 0);
        acc[1][n] = __builtin_amdgcn_mfma_f32_16x16x32_f16(n < 5 ? A1[1].v : A2[1].v, Bv,
                                                           acc[1][n], 0, 0, 0);
      }
    }
  }

  // partial store. C/D: col=lane&15, row=quad*4+reg; tile t -> local rows wave*32+t*16+..
  const int ks96 = ks * 96 + mpos;
#pragma unroll
  for (int t = 0; t < 2; ++t) {
    float* pp = part + ((size_t)ks96 * 128 + wave * 32 + t * 16 + quad * 4) * 132;
#pragma unroll
    for (int r = 0; r < 4; ++r) {
#pragma unroll
      for (int n = 0; n < 4; ++n)
        pp[r * 132 + n * 16 + lr] = acc[t][n][r];
#pragma unroll
      for (int n = 5; n < 9; ++n)
        pp[r * 132 + 64 + (n - 5) * 16 + lr] = acc[t][n][r];
      if (lr == 0) {
        pp[r * 132 + 128] = acc[t][4][r];      // den+ (group 4, col 0)
        pp[r * 132 + 129] = acc[t][9][r];      // den- (group 9, col 0)
      }
    }
  }
}

// ---------------- K3: reduce 8 k-split partials, scale, divide, ELU ----------------------
__global__ __launch_bounds__(256) void k3_final(
    const float* __restrict__ part, const float* __restrict__ f1g,
    const float* __restrict__ f2g, float* __restrict__ out)
{
  const int gid = blockIdx.x * 256 + threadIdx.x;
  const int row = gid >> 6, col = gid & 63;
  const int mpos = row >> 7, r = row & 127;
  float n1 = 0.f, n2 = 0.f, d1 = 0.f, d2 = 0.f;
#pragma unroll
  for (int ks = 0; ks < KSP; ++ks) {
    const float* p = part + ((size_t)(ks * 96 + mpos) * 128 + r) * 132;
    n1 += p[col]; n2 += p[64 + col]; d1 += p[128]; d2 += p[129];
  }
  const float f1 = f1g[row], f2 = f2g[row];
  const float num = f1 * n1 + f2 * n2;
  const float den = fmaxf(f1 * d1 + f2 * d2, 1e-30f);
  const float x = num / den;
  out[gid] = x > 0.f ? x : (expf(x) - 1.f);
}

extern "C" void kernel_launch(void* const* d_in, const int* in_sizes, int n_in,
                              void* d_out, int out_size, void* d_ws, size_t ws_size,
                              hipStream_t stream) {
  const float* inp = (const float*)d_in[0];
  const int* adj = (const int*)d_in[1];
  const float* W = (const float*)d_in[2];
  const float* a = (const float*)d_in[3];

  // ws: Btf 3,932,160 | part 51,904,512 | e1h 24,576 | thh 24,576 | f1g 49,152 | f2g 49,152
  char* ws = (char*)d_ws;
  u16* Btf = (u16*)ws;
  float* part = (float*)(ws + 3932160);
  char* tail = ws + 3932160 + 51904512;
  u16* e1h = (u16*)tail;
  u16* thh = e1h + NN;
  float* f1g = (float*)(thh + NN);
  float* f2g = f1g + NN;

  k1_prep<<<192, 256, 0, stream>>>(inp, W, a, e1h, thh, f1g, f2g, Btf);
  k2_main<<<768, 256, 0, stream>>>(adj, e1h, thh, Btf, part);
  k3_final<<<NN * OUTF / 256, 256, 0, stream>>>(part, f1g, f2g, (float*)d_out);
}

// Round 12
// 867.190 us; speedup vs baseline: 1.2348x; 1.2348x over previous
//
#include <hip/hip_runtime.h>

#define NN 12288
#define OUTF 64
#define ALPHA 0.2f
#define C1 6.0f
#define KSP 8
#define KRANGE (NN / KSP)    /* 1536 per block */
#define ITERS (KRANGE / 64)  /* 24, even */

typedef unsigned short u16;
typedef unsigned int u32;
typedef unsigned long long u64;
typedef _Float16 half8 __attribute__((ext_vector_type(8)));
typedef float floatx4 __attribute__((ext_vector_type(4)));
typedef int intx4 __attribute__((ext_vector_type(4)));

union H16 { u16 u; _Float16 h; };
__device__ __forceinline__ u16 f2h(float f) { H16 c; c.h = (_Float16)f; return c.u; }

// async global->LDS DMA, 16 B per lane; lds dest = wave-uniform base + lane*16
__device__ __forceinline__ void g2l16(const void* g, void* l) {
  __builtin_amdgcn_global_load_lds(
      (const __attribute__((address_space(1))) void*)g,
      (__attribute__((address_space(3))) void*)l, 16, 0, 0);
}

// ---------------- K1: h = X@W, per-node scalars, Btf in MFMA-fragment order --------------
// 192 blocks x 64 nodes. Btf chunk (k32, n): 64 lanes x 16 B contiguous; lane element j' =
// B_row(n*16+lane%16), source node k32*32 + (lane/16)*8 + j'.  B_row r: r<64: e1*h[r];
// r==64: e1; 65..79: 0; 80..143: e2*h[r-80]; r==144: e2; 145..159: 0.
__global__ __launch_bounds__(256) void k1_prep(
    const float* __restrict__ inp, const float* __restrict__ W, const float* __restrict__ a,
    u16* __restrict__ e1h, u16* __restrict__ thh,
    float* __restrict__ f1g, float* __restrict__ f2g, u16* __restrict__ Btf)
{
  __shared__ float Wl[128 * 64];               // 32 KB
  __shared__ float hsm[64][65];                // 16.6 KB
  __shared__ float e1sm[64], e2sm[64];
  const int tid = threadIdx.x, wave = tid >> 6, lane = tid & 63;
  const int b = blockIdx.x;                    // 64-node group
  for (int t = tid; t < 2048; t += 256)
    ((float4*)Wl)[t] = ((const float4*)W)[t];
  const float a1l = a[lane], a2l = a[OUTF + lane];
  __syncthreads();
  for (int jl = 0; jl < 16; ++jl) {
    const int jn = wave * 16 + jl;             // local node 0..63
    const int j = b * 64 + jn;
    const float4* xp = (const float4*)(inp + (size_t)j * 128);
    float h = 0.f;
#pragma unroll
    for (int c4 = 0; c4 < 32; ++c4) {
      float4 v = xp[c4];
      const int k = c4 * 4;
      h += v.x * Wl[k * 64 + lane] + v.y * Wl[(k + 1) * 64 + lane]
         + v.z * Wl[(k + 2) * 64 + lane] + v.w * Wl[(k + 3) * 64 + lane];
    }
    float p1 = h * a1l, p2 = h * a2l;
#pragma unroll
    for (int off = 32; off > 0; off >>= 1) { p1 += __shfl_xor(p1, off); p2 += __shfl_xor(p2, off); }
    hsm[jn][lane] = h;
    if (lane == 0) {
      const float s1 = p1, s2 = p2;
      const float e1 = expf(s2 - C1), e2 = expf(ALPHA * s2);
      e1sm[jn] = e1; e2sm[jn] = e2;
      e1h[j] = f2h(e1);
      thh[j] = f2h(expf(-s1 - C1));            // pos branch iff e1h[j] > thh[i] (u16-monotone)
      f1g[j] = expf(s1 + C1);
      f2g[j] = expf(ALPHA * s1);
    }
  }
  __syncthreads();
  // phase B: block covers 2 full k32 slabs (k32 = b*2+s). 1280 uint4 items, 5/thread.
  for (int cc = tid; cc < 1280; cc += 256) {
    const int s = cc / 640, rem = cc - s * 640;
    const int n = rem >> 6, l = rem & 63;
    const int r = n * 16 + (l & 15);
    const int jb = s * 32 + (l >> 4) * 8;      // local node base for this item's 8 elements
    u32 wpk[4];
#pragma unroll
    for (int p = 0; p < 4; ++p) {
      u16 hh[2];
#pragma unroll
      for (int q2 = 0; q2 < 2; ++q2) {
        const int jj = jb + p * 2 + q2;
        float v;
        if (r < 64)        v = e1sm[jj] * hsm[jj][r];
        else if (r == 64)  v = e1sm[jj];
        else if (r < 80)   v = 0.f;
        else if (r < 144)  v = e2sm[jj] * hsm[jj][r - 80];
        else if (r == 144) v = e2sm[jj];
        else               v = 0.f;
        hh[q2] = f2h(v);
      }
      wpk[p] = (u32)hh[0] | ((u32)hh[1] << 16);
    }
    ((uint4*)Btf)[(size_t)((b * 2 + s) * 10 + n) * 64 + l] = make_uint4(wpk[0], wpk[1], wpk[2], wpk[3]);
  }
}

// pack helper: build branch-resolved mask bytes from an adj register tile (const indices!)
#define PACK_MASKS(dst1, dst2, AJ, EVV)                                                    \
  {                                                                                        \
    u32 ev8[8] = {EVV.x & 0xFFFFu, EVV.x >> 16, EVV.y & 0xFFFFu, EVV.y >> 16,              \
                  EVV.z & 0xFFFFu, EVV.z >> 16, EVV.w & 0xFFFFu, EVV.w >> 16};             \
    _Pragma("unroll")                                                                      \
    for (int p = 0; p < 4; ++p) {                                                          \
      const int av[8] = {AJ[p][0].x, AJ[p][0].y, AJ[p][0].z, AJ[p][0].w,                   \
                         AJ[p][1].x, AJ[p][1].y, AJ[p][1].z, AJ[p][1].w};                  \
      u32 b1 = 0, b2 = 0;                                                                  \
      _Pragma("unroll")                                                                    \
      for (int e = 0; e < 8; ++e) {                                                        \
        const bool nbr = av[e] > 0;                                                        \
        const bool up = ev8[e] > (u32)thu[p];                                              \
        b1 |= (u32)(nbr && up) << e;                                                       \
        b2 |= (u32)(nbr && !up) << e;                                                      \
      }                                                                                    \
      ((unsigned char*)&dst1[p * 32 + prow])[pcol] = (unsigned char)b1;                    \
      ((unsigned char*)&dst2[p * 32 + prow])[pcol] = (unsigned char)b2;                    \
    }                                                                                      \
  }

#define LOAD_ADJ(AJ, EV, koff)                                                             \
  {                                                                                        \
    _Pragma("unroll")                                                                      \
    for (int p = 0; p < 4; ++p) {                                                          \
      AJ[p][0] = __builtin_nontemporal_load((const intx4*)(aB + (size_t)p * 32 * NN + (koff)));      \
      AJ[p][1] = __builtin_nontemporal_load((const intx4*)(aB + (size_t)p * 32 * NN + (koff) + 4));  \
    }                                                                                      \
    EV = *(const uint4*)(eB + (koff));                                                     \
  }

#define DMA_B(buf, slab)                                                                   \
  {                                                                                        \
    const char* src = (const char*)(Btf + ((size_t)(k0 >> 5) + (slab) * 2) * 5120);        \
    _Pragma("unroll")                                                                      \
    for (int i = 0; i < 5; ++i)                                                            \
      g2l16(src + i * 4096 + tid * 16, (char*)&sB[buf][0] + i * 4096 + wave * 1024);       \
  }

#define MFMA_BODY(CUR)                                                                     \
  {                                                                                        \
    u64 w1[2], w2[2];                                                                      \
    w1[0] = m1s[CUR][wave * 32 + lr];      w1[1] = m1s[CUR][wave * 32 + 16 + lr];          \
    w2[0] = m2s[CUR][wave * 32 + lr];      w2[1] = m2s[CUR][wave * 32 + 16 + lr];          \
    _Pragma("unroll")                                                                      \
    for (int h = 0; h < 2; ++h) {                                                          \
      const u32 sh = (u32)(h * 32 + quad * 8);                                             \
      union { half8 v; u16 s[8]; } A1[2], A2[2];                                           \
      const u32 m1a = (u32)(w1[0] >> sh) & 0xFFu, m2a = (u32)(w2[0] >> sh) & 0xFFu;        \
      const u32 m1b = (u32)(w1[1] >> sh) & 0xFFu, m2b = (u32)(w2[1] >> sh) & 0xFFu;        \
      _Pragma("unroll")                                                                    \
      for (int e = 0; e < 8; ++e) {                                                        \
        A1[0].s[e] = ((m1a >> e) & 1u) ? (u16)0x3C00 : (u16)0;                             \
        A2[0].s[e] = ((m2a >> e) & 1u) ? (u16)0x3C00 : (u16)0;                             \
        A1[1].s[e] = ((m1b >> e) & 1u) ? (u16)0x3C00 : (u16)0;                             \
        A2[1].s[e] = ((m2b >> e) & 1u) ? (u16)0x3C00 : (u16)0;                             \
      }                                                                                    \
      const u16* bp = &sB[CUR][h * 5120];                                                  \
      _Pragma("unroll")                                                                    \
      for (int n = 0; n < 10; ++n) {                                                       \
        half8 Bv = *(const half8*)(bp + (n * 64 + lane) * 8);                              \
        acc[0][n] = __builtin_amdgcn_mfma_f32_16x16x32_f16(n < 5 ? A1[0].v : A2[0].v, Bv,  \
                                                           acc[0][n], 0, 0, 0);            \
        acc[1][n] = __builtin_amdgcn_mfma_f32_16x16x32_f16(n < 5 ? A1[1].v : A2[1].v, Bv,  \
                                                           acc[1][n], 0, 0, 0);            \
      }                                                                                    \
    }                                                                                      \
  }

// ---------------- K2: FUSED adj-pack + LDS-staged bit-masked dual GEMM -------------------
// 768 blocks = 96 mpos x 8 ksplit. 2-iteration-ahead adj pipeline, unrolled x2 so all
// register-array indices are compile-time constants (R11's runtime indices caused scratch
// spill: 592 MB WRITE_SIZE). Pack for slab s+1 runs at top of iter s from registers loaded
// during iter s-1 (full-iteration latency cover). One barrier per slab.
__global__ __launch_bounds__(256, 2) void k2_main(
    const int* __restrict__ adj, const u16* __restrict__ e1h, const u16* __restrict__ thh,
    const u16* __restrict__ Btf, float* __restrict__ part)
{
  __shared__ u16 sB[2][10240];                 // 40 KB B slabs
  __shared__ u64 m1s[2][128];                  // 2 KB pos-branch masks
  __shared__ u64 m2s[2][128];                  // 2 KB neg-branch masks
  const int tid = threadIdx.x;
  const int wave = tid >> 6, lane = tid & 63;
  const int quad = lane >> 4, lr = lane & 15;
  const int mpos = (int)blockIdx.x >> 3;
  const int ks = (int)blockIdx.x & 7;
  const int mbase = mpos * 128;
  const int k0 = ks * KRANGE;

  // pack role: rows prow+32p (p=0..3), cols pcol*8..+8 of each k64 slab
  const int prow = tid >> 3, pcol = tid & 7;
  u16 thu[4];
#pragma unroll
  for (int p = 0; p < 4; ++p) thu[p] = thh[mbase + p * 32 + prow];
  const int* aB = adj + (size_t)(mbase + prow) * NN + k0 + pcol * 8;
  const u16* eB = e1h + k0 + pcol * 8;

  floatx4 acc[2][10];
#pragma unroll
  for (int t = 0; t < 2; ++t)
#pragma unroll
    for (int n = 0; n < 10; ++n) acc[t][n] = (floatx4){0.f, 0.f, 0.f, 0.f};

  intx4 ajb0[4][2], ajb1[4][2];                // named buffers: constant indices only
  uint4 ev0, ev1;

  // ---- prologue: B slab 0 via DMA; adj slab 0 -> ajb0, pack m[0]; adj slab 1 -> ajb1 ----
  DMA_B(0, 0)
  LOAD_ADJ(ajb0, ev0, 0)
  PACK_MASKS(m1s[0], m2s[0], ajb0, ev0)
  LOAD_ADJ(ajb1, ev1, 64)

  for (int it = 0; it < ITERS; it += 2) {
    // ---- even slab: compute buf 0; pack slab it+1 (from ajb1); refill ajb0 <- it+2 ----
    __syncthreads();
    if (it + 1 < ITERS) {
      DMA_B(1, it + 1)
      PACK_MASKS(m1s[1], m2s[1], ajb1, ev1)
    }
    if (it + 2 < ITERS) LOAD_ADJ(ajb0, ev0, (it + 2) * 64)
    MFMA_BODY(0)
    // ---- odd slab: compute buf 1; pack slab it+2 (from ajb0); refill ajb1 <- it+3 ----
    __syncthreads();
    if (it + 2 < ITERS) {
      DMA_B(0, it + 2)
      PACK_MASKS(m1s[0], m2s[0], ajb0, ev0)
    }
    if (it + 3 < ITERS) LOAD_ADJ(ajb1, ev1, (it + 3) * 64)
    MFMA_BODY(1)
  }

  // partial store. C/D: col=lane&15, row=quad*4+reg; tile t -> local rows wave*32+t*16+..
  const int ks96 = ks * 96 + mpos;
#pragma unroll
  for (int t = 0; t < 2; ++t) {
    float* pp = part + ((size_t)ks96 * 128 + wave * 32 + t * 16 + quad * 4) * 132;
#pragma unroll
    for (int r = 0; r < 4; ++r) {
#pragma unroll
      for (int n = 0; n < 4; ++n)
        pp[r * 132 + n * 16 + lr] = acc[t][n][r];
#pragma unroll
      for (int n = 5; n < 9; ++n)
        pp[r * 132 + 64 + (n - 5) * 16 + lr] = acc[t][n][r];
      if (lr == 0) {
        pp[r * 132 + 128] = acc[t][4][r];      // den+ (group 4, col 0)
        pp[r * 132 + 129] = acc[t][9][r];      // den- (group 9, col 0)
      }
    }
  }
}

// ---------------- K3: reduce 8 k-split partials, scale, divide, ELU ----------------------
__global__ __launch_bounds__(256) void k3_final(
    const float* __restrict__ part, const float* __restrict__ f1g,
    const float* __restrict__ f2g, float* __restrict__ out)
{
  const int gid = blockIdx.x * 256 + threadIdx.x;
  const int row = gid >> 6, col = gid & 63;
  const int mpos = row >> 7, r = row & 127;
  float n1 = 0.f, n2 = 0.f, d1 = 0.f, d2 = 0.f;
#pragma unroll
  for (int ks = 0; ks < KSP; ++ks) {
    const float* p = part + ((size_t)(ks * 96 + mpos) * 128 + r) * 132;
    n1 += p[col]; n2 += p[64 + col]; d1 += p[128]; d2 += p[129];
  }
  const float f1 = f1g[row], f2 = f2g[row];
  const float num = f1 * n1 + f2 * n2;
  const float den = fmaxf(f1 * d1 + f2 * d2, 1e-30f);
  const float x = num / den;
  out[gid] = x > 0.f ? x : (expf(x) - 1.f);
}

extern "C" void kernel_launch(void* const* d_in, const int* in_sizes, int n_in,
                              void* d_out, int out_size, void* d_ws, size_t ws_size,
                              hipStream_t stream) {
  const float* inp = (const float*)d_in[0];
  const int* adj = (const int*)d_in[1];
  const float* W = (const float*)d_in[2];
  const float* a = (const float*)d_in[3];

  // ws: Btf 3,932,160 | part 51,904,512 | e1h 24,576 | thh 24,576 | f1g 49,152 | f2g 49,152
  char* ws = (char*)d_ws;
  u16* Btf = (u16*)ws;
  float* part = (float*)(ws + 3932160);
  char* tail = ws + 3932160 + 51904512;
  u16* e1h = (u16*)tail;
  u16* thh = e1h + NN;
  float* f1g = (float*)(thh + NN);
  float* f2g = f1g + NN;

  k1_prep<<<192, 256, 0, stream>>>(inp, W, a, e1h, thh, f1g, f2g, Btf);
  k2_main<<<768, 256, 0, stream>>>(adj, e1h, thh, Btf, part);
  k3_final<<<NN * OUTF / 256, 256, 0, stream>>>(part, f1g, f2g, (float*)d_out);
}